// Round 1
// baseline (442.243 us; speedup 1.0000x reference)
//
#include <hip/hip_runtime.h>
#include <hip/hip_bf16.h>

typedef unsigned short u16;
typedef __attribute__((ext_vector_type(8))) __bf16 bf16x8;
typedef __attribute__((ext_vector_type(4))) float f32x4;

#define MODEL_DIM 1024
#define NUM_HEADS 16
#define HEAD_DIM  64
#define BATCH     4
#define SEQ       2048
#define ROWS      (BATCH*SEQ)     // 8192

static __device__ __forceinline__ u16 f2bf(float f) {
    union { __hip_bfloat16 h; u16 u; } cv;
    cv.h = __float2bfloat16(f);
    return cv.u;
}

// ---------------- cast f32 -> bf16 ----------------
__global__ void castk(const float* __restrict__ in, u16* __restrict__ out, int n) {
    int i = (blockIdx.x * blockDim.x + threadIdx.x) * 4;
    int stride = gridDim.x * blockDim.x * 4;
    for (; i < n; i += stride) {
        float4 v = *reinterpret_cast<const float4*>(in + i);
        ushort4 o;
        o.x = f2bf(v.x); o.y = f2bf(v.y); o.z = f2bf(v.z); o.w = f2bf(v.w);
        *reinterpret_cast<ushort4*>(out + i) = o;
    }
}

// ---------------- NT GEMM: C[M,N] = A[M,K] * W[N,K]^T ----------------
// EPI==0: write bf16 to qkv buffer laid out [B][H][N][D]
// EPI==1: write f32 + bias to outF [M][N]
#define BM 128
#define BN 128
#define BK 64
#define LDST 72   // LDS row stride in bf16 elems: 144B, 16B-aligned, 2-way bank alias (free)

template<int EPI>
__global__ __launch_bounds__(256) void gemm_bt(
    const u16* __restrict__ A,   // [M,K] bf16
    const u16* __restrict__ W,   // [N,K] bf16
    u16* __restrict__ outB,
    float* __restrict__ outF,
    const float* __restrict__ bias,
    int M, int N, int K)
{
    __shared__ u16 As[BM * LDST];
    __shared__ u16 Bs[BN * LDST];
    const int t    = threadIdx.x;
    const int wid  = t >> 6;
    const int lane = t & 63;
    const int lo   = lane & 15, hi = lane >> 4;
    const int bm   = blockIdx.x * BM;
    const int bn   = blockIdx.y * BN;
    const int wr   = wid >> 1, wc = wid & 1;

    f32x4 acc[4][4];
#pragma unroll
    for (int m = 0; m < 4; m++)
#pragma unroll
        for (int n = 0; n < 4; n++) acc[m][n] = (f32x4){0.f, 0.f, 0.f, 0.f};

    for (int k0 = 0; k0 < K; k0 += BK) {
        __syncthreads();
#pragma unroll
        for (int i = 0; i < 4; i++) {
            int a   = t + 256 * i;
            int row = a >> 3, ch = (a & 7) * 8;
            uint4 va = *reinterpret_cast<const uint4*>(A + (size_t)(bm + row) * K + k0 + ch);
            *reinterpret_cast<uint4*>(As + row * LDST + ch) = va;
            uint4 vb = *reinterpret_cast<const uint4*>(W + (size_t)(bn + row) * K + k0 + ch);
            *reinterpret_cast<uint4*>(Bs + row * LDST + ch) = vb;
        }
        __syncthreads();
#pragma unroll
        for (int h = 0; h < 2; h++) {
            bf16x8 af[4], bfr[4];
#pragma unroll
            for (int m = 0; m < 4; m++)
                af[m] = *reinterpret_cast<const bf16x8*>(As + (wr * 64 + m * 16 + lo) * LDST + h * 32 + hi * 8);
#pragma unroll
            for (int n = 0; n < 4; n++)
                bfr[n] = *reinterpret_cast<const bf16x8*>(Bs + (wc * 64 + n * 16 + lo) * LDST + h * 32 + hi * 8);
#pragma unroll
            for (int m = 0; m < 4; m++)
#pragma unroll
                for (int n = 0; n < 4; n++)
                    acc[m][n] = __builtin_amdgcn_mfma_f32_16x16x32_bf16(af[m], bfr[n], acc[m][n], 0, 0, 0);
        }
    }

#pragma unroll
    for (int m = 0; m < 4; m++) {
#pragma unroll
        for (int n = 0; n < 4; n++) {
#pragma unroll
            for (int r = 0; r < 4; r++) {
                int row = bm + wr * 64 + m * 16 + hi * 4 + r;
                int col = bn + wc * 64 + n * 16 + lo;
                float v = acc[m][n][r];
                if (EPI == 0) {
                    int b = row >> 11, np = row & 2047;
                    int hh = col >> 6, dd = col & 63;
                    outB[(((size_t)(b * NUM_HEADS + hh) * SEQ + np) << 6) + dd] = f2bf(v);
                } else {
                    outF[(size_t)row * N + col] = v + bias[col];
                }
            }
        }
    }
}

// ---------------- flash attention (causal), bf16 in/out ----------------
// grid: x = N/64 (q block), y = B*H. 256 threads = 4 waves, each wave owns 16 q rows.
__global__ __launch_bounds__(256) void attn(
    const u16* __restrict__ Q,   // [B*H][N][64]
    const u16* __restrict__ Kg,
    const u16* __restrict__ Vg,
    u16* __restrict__ O)         // [B][N][H][64]
{
    __shared__ u16 Ks[64 * 72];
    __shared__ u16 Vt[64 * 72];   // transposed: [d][kv]
    __shared__ u16 Ps[4][16 * 72];
    const int t    = threadIdx.x;
    const int wid  = t >> 6, lane = t & 63;
    const int lo   = lane & 15, hi = lane >> 4;
    const int qb   = blockIdx.x;          // 0..31
    const int bh   = blockIdx.y;          // 0..63
    const size_t base = (size_t)bh * SEQ * 64;

    bf16x8 qf[2];
    const int qrow = qb * 64 + wid * 16 + lo;
#pragma unroll
    for (int h = 0; h < 2; h++)
        qf[h] = *reinterpret_cast<const bf16x8*>(Q + base + (size_t)qrow * 64 + h * 32 + hi * 8);

    float m_run[4], l_run[4];
    f32x4 o_acc[4];
#pragma unroll
    for (int r = 0; r < 4; r++) { m_run[r] = -3.0e38f; l_run[r] = 0.f; }
#pragma unroll
    for (int dt = 0; dt < 4; dt++) o_acc[dt] = (f32x4){0.f, 0.f, 0.f, 0.f};

    for (int j = 0; j <= qb; j++) {
        __syncthreads();
        // stage K rows and V transposed
#pragma unroll
        for (int i = 0; i < 2; i++) {
            int a = t + 256 * i;
            int row = a >> 3, ch = (a & 7) * 8;
            uint4 kv = *reinterpret_cast<const uint4*>(Kg + base + (size_t)(j * 64 + row) * 64 + ch);
            *reinterpret_cast<uint4*>(Ks + row * 72 + ch) = kv;
            union { uint4 v; u16 s[8]; } tv;
            tv.v = *reinterpret_cast<const uint4*>(Vg + base + (size_t)(j * 64 + row) * 64 + ch);
#pragma unroll
            for (int e = 0; e < 8; e++)
                Vt[(ch + e) * 72 + row] = tv.s[e];
        }
        __syncthreads();

        // scores S = Q K^T * scale (C-layout: col=lo, row=hi*4+r)
        f32x4 s[4];
#pragma unroll
        for (int kt = 0; kt < 4; kt++) {
            f32x4 a = (f32x4){0.f, 0.f, 0.f, 0.f};
#pragma unroll
            for (int h = 0; h < 2; h++) {
                bf16x8 kf = *reinterpret_cast<const bf16x8*>(Ks + (kt * 16 + lo) * 72 + h * 32 + hi * 8);
                a = __builtin_amdgcn_mfma_f32_16x16x32_bf16(qf[h], kf, a, 0, 0, 0);
            }
            s[kt] = a * 0.125f;
        }
        if (j == qb) {
#pragma unroll
            for (int kt = 0; kt < 4; kt++)
#pragma unroll
                for (int r = 0; r < 4; r++) {
                    int cg = j * 64 + kt * 16 + lo;
                    int rg = qb * 64 + wid * 16 + hi * 4 + r;
                    if (cg > rg) s[kt][r] = -1e30f;
                }
        }

        // online softmax
        float pex[4][4];   // [kt][r]
#pragma unroll
        for (int r = 0; r < 4; r++) {
            float vm = fmaxf(fmaxf(s[0][r], s[1][r]), fmaxf(s[2][r], s[3][r]));
#pragma unroll
            for (int m = 1; m < 16; m <<= 1) vm = fmaxf(vm, __shfl_xor(vm, m));
            float nm = fmaxf(m_run[r], vm);
            float sc = __expf(m_run[r] - nm);
            m_run[r] = nm;
            float ps = 0.f;
#pragma unroll
            for (int kt = 0; kt < 4; kt++) {
                float p = __expf(s[kt][r] - nm);
                pex[kt][r] = p;
                ps += p;
            }
#pragma unroll
            for (int m = 1; m < 16; m <<= 1) ps += __shfl_xor(ps, m);
            l_run[r] = l_run[r] * sc + ps;
#pragma unroll
            for (int dt = 0; dt < 4; dt++) o_acc[dt][r] *= sc;
        }

        // P -> per-wave LDS (C-layout -> A-fragment layout round-trip)
#pragma unroll
        for (int kt = 0; kt < 4; kt++)
#pragma unroll
            for (int r = 0; r < 4; r++)
                Ps[wid][(hi * 4 + r) * 72 + kt * 16 + lo] = f2bf(pex[kt][r]);
        asm volatile("s_waitcnt lgkmcnt(0)" ::: "memory");

        // O += P V
        bf16x8 pa[2];
#pragma unroll
        for (int h = 0; h < 2; h++)
            pa[h] = *reinterpret_cast<const bf16x8*>(Ps[wid] + lo * 72 + h * 32 + hi * 8);
#pragma unroll
        for (int dt = 0; dt < 4; dt++)
#pragma unroll
            for (int h = 0; h < 2; h++) {
                bf16x8 vf = *reinterpret_cast<const bf16x8*>(Vt + (dt * 16 + lo) * 72 + h * 32 + hi * 8);
                o_acc[dt] = __builtin_amdgcn_mfma_f32_16x16x32_bf16(pa[h], vf, o_acc[dt], 0, 0, 0);
            }
    }

    // epilogue: O[b][n][h][d] bf16
    const int b = bh >> 4, hh = bh & 15;
#pragma unroll
    for (int dt = 0; dt < 4; dt++)
#pragma unroll
        for (int r = 0; r < 4; r++) {
            int qg = qb * 64 + wid * 16 + hi * 4 + r;
            int dd = dt * 16 + lo;
            float v = o_acc[dt][r] / l_run[r];
            O[(((size_t)b * SEQ + qg) * NUM_HEADS + hh) * 64 + dd] = f2bf(v);
        }
}

extern "C" void kernel_launch(void* const* d_in, const int* in_sizes, int n_in,
                              void* d_out, int out_size, void* d_ws, size_t ws_size,
                              hipStream_t stream) {
    const float* x  = (const float*)d_in[0];
    const float* Wq = (const float*)d_in[1];
    const float* Wk = (const float*)d_in[2];
    const float* Wv = (const float*)d_in[3];
    const float* Wo = (const float*)d_in[4];
    const float* bo = (const float*)d_in[5];
    float* out = (float*)d_out;

    char* ws = (char*)d_ws;
    u16* xb  = (u16*)ws;                              // 8192*1024        (16 MiB)
    u16* wqb = (u16*)(ws + 16777216);                 // 1024*1024 each
    u16* wkb = wqb + 1048576;
    u16* wvb = wkb + 1048576;
    u16* wob = wvb + 1048576;
    u16* q   = (u16*)(ws + 16777216 + 8388608);       // [B][H][N][D] bf16 (16 MiB)
    u16* k   = q + 8388608;
    u16* v   = k + 8388608;
    u16* ao  = v + 8388608;                           // [B][N][H*D] bf16 (16 MiB)

    castk<<<2048, 256, 0, stream>>>(x,  xb,  ROWS * MODEL_DIM);
    castk<<<1024, 256, 0, stream>>>(Wq, wqb, MODEL_DIM * MODEL_DIM);
    castk<<<1024, 256, 0, stream>>>(Wk, wkb, MODEL_DIM * MODEL_DIM);
    castk<<<1024, 256, 0, stream>>>(Wv, wvb, MODEL_DIM * MODEL_DIM);
    castk<<<1024, 256, 0, stream>>>(Wo, wob, MODEL_DIM * MODEL_DIM);

    dim3 ggrid(ROWS / BM, MODEL_DIM / BN);
    gemm_bt<0><<<ggrid, 256, 0, stream>>>(xb, wqb, q, nullptr, nullptr, ROWS, MODEL_DIM, MODEL_DIM);
    gemm_bt<0><<<ggrid, 256, 0, stream>>>(xb, wkb, k, nullptr, nullptr, ROWS, MODEL_DIM, MODEL_DIM);
    gemm_bt<0><<<ggrid, 256, 0, stream>>>(xb, wvb, v, nullptr, nullptr, ROWS, MODEL_DIM, MODEL_DIM);

    attn<<<dim3(SEQ / 64, BATCH * NUM_HEADS), 256, 0, stream>>>(q, k, v, ao);

    gemm_bt<1><<<ggrid, 256, 0, stream>>>(ao, wob, nullptr, out, bo, ROWS, MODEL_DIM, MODEL_DIM);
}

// Round 2
// 292.965 us; speedup vs baseline: 1.5095x; 1.5095x over previous
//
#include <hip/hip_runtime.h>
#include <hip/hip_bf16.h>

typedef unsigned short u16;
typedef __attribute__((ext_vector_type(8))) __bf16 bf16x8;
typedef __attribute__((ext_vector_type(4))) float f32x4;
typedef __attribute__((ext_vector_type(2))) unsigned int u32x2;

#define MODEL_DIM 1024
#define NUM_HEADS 16
#define HEAD_DIM  64
#define BATCH     4
#define SEQ       2048
#define ROWS      (BATCH*SEQ)     // 8192

static __device__ __forceinline__ u16 f2bf(float f) {
    union { __hip_bfloat16 h; u16 u; } cv;
    cv.h = __float2bfloat16(f);
    return cv.u;
}

// ---------------- cast f32 -> bf16 ----------------
__global__ void castk(const float* __restrict__ in, u16* __restrict__ out, int n) {
    int i = (blockIdx.x * blockDim.x + threadIdx.x) * 4;
    int stride = gridDim.x * blockDim.x * 4;
    for (; i < n; i += stride) {
        float4 v = *reinterpret_cast<const float4*>(in + i);
        ushort4 o;
        o.x = f2bf(v.x); o.y = f2bf(v.y); o.z = f2bf(v.z); o.w = f2bf(v.w);
        *reinterpret_cast<ushort4*>(out + i) = o;
    }
}

// ---------------- NT GEMM: C[M,N] = A[M,K] * W[N,K]^T ----------------
#define BM 128
#define BN 128
#define BK 64
#define LDST 72

template<int EPI>
__global__ __launch_bounds__(256) void gemm_bt(
    const u16* __restrict__ A,   // [M,K] bf16
    const u16* __restrict__ W,   // [N,K] bf16
    u16* __restrict__ outB,
    float* __restrict__ outF,
    const float* __restrict__ bias,
    int M, int N, int K)
{
    __shared__ u16 As[BM * LDST];
    __shared__ u16 Bs[BN * LDST];
    const int t    = threadIdx.x;
    const int wid  = t >> 6;
    const int lane = t & 63;
    const int lo   = lane & 15, hi = lane >> 4;
    const int bm   = blockIdx.x * BM;
    const int bn   = blockIdx.y * BN;
    const int wr   = wid >> 1, wc = wid & 1;

    f32x4 acc[4][4];
#pragma unroll
    for (int m = 0; m < 4; m++)
#pragma unroll
        for (int n = 0; n < 4; n++) acc[m][n] = (f32x4){0.f, 0.f, 0.f, 0.f};

    for (int k0 = 0; k0 < K; k0 += BK) {
        __syncthreads();
#pragma unroll
        for (int i = 0; i < 4; i++) {
            int a   = t + 256 * i;
            int row = a >> 3, ch = (a & 7) * 8;
            uint4 va = *reinterpret_cast<const uint4*>(A + (size_t)(bm + row) * K + k0 + ch);
            *reinterpret_cast<uint4*>(As + row * LDST + ch) = va;
            uint4 vb = *reinterpret_cast<const uint4*>(W + (size_t)(bn + row) * K + k0 + ch);
            *reinterpret_cast<uint4*>(Bs + row * LDST + ch) = vb;
        }
        __syncthreads();
#pragma unroll
        for (int h = 0; h < 2; h++) {
            bf16x8 af[4], bfr[4];
#pragma unroll
            for (int m = 0; m < 4; m++)
                af[m] = *reinterpret_cast<const bf16x8*>(As + (wr * 64 + m * 16 + lo) * LDST + h * 32 + hi * 8);
#pragma unroll
            for (int n = 0; n < 4; n++)
                bfr[n] = *reinterpret_cast<const bf16x8*>(Bs + (wc * 64 + n * 16 + lo) * LDST + h * 32 + hi * 8);
#pragma unroll
            for (int m = 0; m < 4; m++)
#pragma unroll
                for (int n = 0; n < 4; n++)
                    acc[m][n] = __builtin_amdgcn_mfma_f32_16x16x32_bf16(af[m], bfr[n], acc[m][n], 0, 0, 0);
        }
    }

#pragma unroll
    for (int m = 0; m < 4; m++) {
#pragma unroll
        for (int n = 0; n < 4; n++) {
#pragma unroll
            for (int r = 0; r < 4; r++) {
                int row = bm + wr * 64 + m * 16 + hi * 4 + r;
                int col = bn + wc * 64 + n * 16 + lo;
                float v = acc[m][n][r];
                if (EPI == 0) {
                    int b = row >> 11, np = row & 2047;
                    int hh = col >> 6, dd = col & 63;
                    outB[(((size_t)(b * NUM_HEADS + hh) * SEQ + np) << 6) + dd] = f2bf(v);
                } else {
                    outF[(size_t)row * N + col] = v + bias[col];
                }
            }
        }
    }
}

// ---------------- flash attention v2: swapped QK^T, in-register P, tr-read V ----
// grid: x = N/128 (q tile, reversed), y = B*H. 256 threads = 4 waves, 32 q rows/wave.

static __device__ __forceinline__ u32x2 tr16(unsigned int addr) {
    u32x2 r;
    asm volatile("ds_read_b64_tr_b16 %0, %1" : "=v"(r) : "v"(addr));
    return r;
}

__global__ __launch_bounds__(256) void attn(
    const u16* __restrict__ Q,   // [B*H][N][64]
    const u16* __restrict__ Kg,
    const u16* __restrict__ Vg,
    u16* __restrict__ O)         // [B][N][H][64]
{
    __shared__ u16 Ks[64 * 72];        // row-major, padded
    __shared__ u16 Vs[64 * 64];        // subtiled: off=((kv>>5)*4+(d>>4))*512+(kv&31)*16+(d&15)
    const int t    = threadIdx.x;
    const int wid  = t >> 6, lane = t & 63;
    const int lo   = lane & 15, hi = lane >> 4;
    const int qt   = (int)gridDim.x - 1 - (int)blockIdx.x;   // longest blocks first
    const int bh   = blockIdx.y;
    const size_t base = (size_t)bh * SEQ * 64;
    const int qbase = qt * 128 + wid * 32;

    // Q fragments (B-operand layout): lane holds Q[qbase+m*16+lo][h*32+hi*8+..]
    bf16x8 qf[2][2];
#pragma unroll
    for (int m = 0; m < 2; m++)
#pragma unroll
        for (int h = 0; h < 2; h++)
            qf[m][h] = *reinterpret_cast<const bf16x8*>(Q + base + (size_t)(qbase + m * 16 + lo) * 64 + h * 32 + hi * 8);

    float m_run[2], l_run[2];
    f32x4 acc[2][4];
#pragma unroll
    for (int m = 0; m < 2; m++) {
        m_run[m] = -3.0e38f; l_run[m] = 0.f;
#pragma unroll
        for (int dt = 0; dt < 4; dt++) acc[m][dt] = (f32x4){0.f, 0.f, 0.f, 0.f};
    }

    const int jmax_blk = (qt * 128 + 127) >> 6;
    const int jmax_wav = (qbase + 31) >> 6;
    const unsigned int vtb = (unsigned int)(uintptr_t)Vs + (unsigned int)((hi * 64 + lo * 4) * 2);
    const float C = 0.125f * 1.44269504f;   // scale * log2(e)

    for (int j = 0; j <= jmax_blk; j++) {
        __syncthreads();
#pragma unroll
        for (int i = 0; i < 2; i++) {
            int a = t + 256 * i;
            int row = a >> 3, ch = (a & 7) * 8;
            uint4 kv = *reinterpret_cast<const uint4*>(Kg + base + (size_t)(j * 64 + row) * 64 + ch);
            *reinterpret_cast<uint4*>(Ks + row * 72 + ch) = kv;
            uint4 vv = *reinterpret_cast<const uint4*>(Vg + base + (size_t)(j * 64 + row) * 64 + ch);
            *reinterpret_cast<uint4*>(Vs + ((row >> 5) * 4 + (ch >> 4)) * 512 + (row & 31) * 16 + (ch & 15)) = vv;
        }
        __syncthreads();
        if (j > jmax_wav) continue;     // fully-masked tile for this wave

        // K fragments (A-operand): K[j*64+kt*16+lo][h*32+hi*8+..]
        bf16x8 kf[4][2];
#pragma unroll
        for (int kt = 0; kt < 4; kt++)
#pragma unroll
            for (int h = 0; h < 2; h++)
                kf[kt][h] = *reinterpret_cast<const bf16x8*>(Ks + (kt * 16 + lo) * 72 + h * 32 + hi * 8);

        bf16x8 pa[2][2];
#pragma unroll
        for (int m = 0; m < 2; m++) {
            // S^T = K Q^T: lane holds S[q=qbase+m*16+lo][kv=j*64+kt*16+hi*4+r]
            f32x4 s[4];
#pragma unroll
            for (int kt = 0; kt < 4; kt++) {
                f32x4 a = (f32x4){0.f, 0.f, 0.f, 0.f};
#pragma unroll
                for (int h = 0; h < 2; h++)
                    a = __builtin_amdgcn_mfma_f32_16x16x32_bf16(kf[kt][h], qf[m][h], a, 0, 0, 0);
                s[kt] = a * C;
            }
            const int qfb = qbase + m * 16;
            if (j * 64 + 63 > qfb) {    // diagonal tile: causal mask
                const int q = qfb + lo;
#pragma unroll
                for (int kt = 0; kt < 4; kt++)
#pragma unroll
                    for (int r = 0; r < 4; r++)
                        if (j * 64 + kt * 16 + hi * 4 + r > q) s[kt][r] = -1.0e30f;
            }
            // online softmax (row q=lo local to 4 lanes {lo,lo+16,lo+32,lo+48})
            float vm = s[0][0];
#pragma unroll
            for (int kt = 0; kt < 4; kt++)
#pragma unroll
                for (int r = 0; r < 4; r++) vm = fmaxf(vm, s[kt][r]);
            vm = fmaxf(vm, __shfl_xor(vm, 16));
            vm = fmaxf(vm, __shfl_xor(vm, 32));
            float nm = fmaxf(m_run[m], vm);
            float sc = exp2f(m_run[m] - nm);
            m_run[m] = nm;
            float ps = 0.f;
#pragma unroll
            for (int kt = 0; kt < 4; kt++)
#pragma unroll
                for (int r = 0; r < 4; r++) {
                    float p = exp2f(s[kt][r] - nm);
                    s[kt][r] = p;
                    ps += p;
                }
            ps += __shfl_xor(ps, 16);
            ps += __shfl_xor(ps, 32);
            l_run[m] = l_run[m] * sc + ps;
            // rescale O (acc rows are q=hi*4+r; fetch sc from lane hi*4+r)
            float sc4[4];
#pragma unroll
            for (int r = 0; r < 4; r++) sc4[r] = __shfl(sc, hi * 4 + r);
#pragma unroll
            for (int dt = 0; dt < 4; dt++)
#pragma unroll
                for (int r = 0; r < 4; r++) acc[m][dt][r] *= sc4[r];
            // pack P into PV A-fragments (kappa order: e<4 -> kv=4hi+e; e>=4 -> 16+4hi+e-4)
            union { u16 u[8]; bf16x8 v; } pk0, pk1;
#pragma unroll
            for (int e = 0; e < 4; e++) {
                pk0.u[e]     = f2bf(s[0][e]);
                pk0.u[4 + e] = f2bf(s[1][e]);
                pk1.u[e]     = f2bf(s[2][e]);
                pk1.u[4 + e] = f2bf(s[3][e]);
            }
            pa[m][0] = pk0.v;
            pa[m][1] = pk1.v;
        }

        // PV: B-operand via hardware transpose reads of subtiled V
        u32x2 tv[4][2][2];
#pragma unroll
        for (int dt = 0; dt < 4; dt++)
#pragma unroll
            for (int h = 0; h < 2; h++)
#pragma unroll
                for (int sel = 0; sel < 2; sel++)
                    tv[dt][h][sel] = tr16(vtb + (unsigned)(((h * 4 + dt) * 512 + sel * 256) * 2));
        asm volatile("s_waitcnt lgkmcnt(0)" ::: "memory");
        __builtin_amdgcn_sched_barrier(0);
#pragma unroll
        for (int dt = 0; dt < 4; dt++) {
#pragma unroll
            for (int h = 0; h < 2; h++) {
                union { unsigned int w[4]; bf16x8 v; } bv;
                bv.w[0] = tv[dt][h][0][0];
                bv.w[1] = tv[dt][h][0][1];
                bv.w[2] = tv[dt][h][1][0];
                bv.w[3] = tv[dt][h][1][1];
#pragma unroll
                for (int m = 0; m < 2; m++)
                    acc[m][dt] = __builtin_amdgcn_mfma_f32_16x16x32_bf16(pa[m][h], bv.v, acc[m][dt], 0, 0, 0);
            }
        }
    }

    // epilogue: O[b][n][h][d] bf16
    const int b = bh >> 4, hh = bh & 15;
#pragma unroll
    for (int m = 0; m < 2; m++) {
        float inv[4];
#pragma unroll
        for (int r = 0; r < 4; r++) {
            float lr = __shfl(l_run[m], hi * 4 + r);
            inv[r] = 1.0f / lr;
        }
#pragma unroll
        for (int dt = 0; dt < 4; dt++)
#pragma unroll
            for (int r = 0; r < 4; r++) {
                int qg = qbase + m * 16 + hi * 4 + r;
                int dd = dt * 16 + lo;
                O[(((size_t)b * SEQ + qg) * NUM_HEADS + hh) * 64 + dd] = f2bf(acc[m][dt][r] * inv[r]);
            }
    }
}

extern "C" void kernel_launch(void* const* d_in, const int* in_sizes, int n_in,
                              void* d_out, int out_size, void* d_ws, size_t ws_size,
                              hipStream_t stream) {
    const float* x  = (const float*)d_in[0];
    const float* Wq = (const float*)d_in[1];
    const float* Wk = (const float*)d_in[2];
    const float* Wv = (const float*)d_in[3];
    const float* Wo = (const float*)d_in[4];
    const float* bo = (const float*)d_in[5];
    float* out = (float*)d_out;

    char* ws = (char*)d_ws;
    u16* xb  = (u16*)ws;                              // 16 MiB
    u16* wqb = (u16*)(ws + 16777216);
    u16* wkb = wqb + 1048576;
    u16* wvb = wkb + 1048576;
    u16* wob = wvb + 1048576;
    u16* q   = (u16*)(ws + 16777216 + 8388608);       // [B][H][N][D] bf16
    u16* k   = q + 8388608;
    u16* v   = k + 8388608;
    u16* ao  = v + 8388608;                           // [B][N][H*D] bf16

    castk<<<2048, 256, 0, stream>>>(x,  xb,  ROWS * MODEL_DIM);
    castk<<<1024, 256, 0, stream>>>(Wq, wqb, MODEL_DIM * MODEL_DIM);
    castk<<<1024, 256, 0, stream>>>(Wk, wkb, MODEL_DIM * MODEL_DIM);
    castk<<<1024, 256, 0, stream>>>(Wv, wvb, MODEL_DIM * MODEL_DIM);
    castk<<<1024, 256, 0, stream>>>(Wo, wob, MODEL_DIM * MODEL_DIM);

    dim3 ggrid(ROWS / BM, MODEL_DIM / BN);
    gemm_bt<0><<<ggrid, 256, 0, stream>>>(xb, wqb, q, nullptr, nullptr, ROWS, MODEL_DIM, MODEL_DIM);
    gemm_bt<0><<<ggrid, 256, 0, stream>>>(xb, wkb, k, nullptr, nullptr, ROWS, MODEL_DIM, MODEL_DIM);
    gemm_bt<0><<<ggrid, 256, 0, stream>>>(xb, wvb, v, nullptr, nullptr, ROWS, MODEL_DIM, MODEL_DIM);

    attn<<<dim3(SEQ / 128, BATCH * NUM_HEADS), 256, 0, stream>>>(q, k, v, ao);

    gemm_bt<1><<<ggrid, 256, 0, stream>>>(ao, wob, nullptr, out, bo, ROWS, MODEL_DIM, MODEL_DIM);
}

// Round 3
// 281.637 us; speedup vs baseline: 1.5703x; 1.0402x over previous
//
#include <hip/hip_runtime.h>
#include <hip/hip_bf16.h>

typedef unsigned short u16;
typedef __attribute__((ext_vector_type(8))) __bf16 bf16x8;
typedef __attribute__((ext_vector_type(4))) float f32x4;
typedef __attribute__((ext_vector_type(2))) unsigned int u32x2;

#define MODEL_DIM 1024
#define NUM_HEADS 16
#define HEAD_DIM  64
#define BATCH     4
#define SEQ       2048
#define ROWS      (BATCH*SEQ)     // 8192

static __device__ __forceinline__ u16 f2bf(float f) {
    union { __hip_bfloat16 h; u16 u; } cv;
    cv.h = __float2bfloat16(f);
    return cv.u;
}

static __device__ __forceinline__ void gload16(const u16* g, unsigned lds_byte) {
    __builtin_amdgcn_global_load_lds(
        (const __attribute__((address_space(1))) unsigned int*)g,
        (__attribute__((address_space(3))) unsigned int*)(uintptr_t)lds_byte,
        16, 0, 0);
}

// ---------------- cast f32 -> bf16 ----------------
__global__ void castk(const float* __restrict__ in, u16* __restrict__ out, int n) {
    int i = (blockIdx.x * blockDim.x + threadIdx.x) * 4;
    int stride = gridDim.x * blockDim.x * 4;
    for (; i < n; i += stride) {
        float4 v = *reinterpret_cast<const float4*>(in + i);
        ushort4 o;
        o.x = f2bf(v.x); o.y = f2bf(v.y); o.z = f2bf(v.z); o.w = f2bf(v.w);
        *reinterpret_cast<ushort4*>(out + i) = o;
    }
}

// ---------------- NT GEMM: C[M,N] = A[M,K] * W[N,K]^T ----------------
#define BM 128
#define BN 128
#define BK 64
#define LDST 72

template<int EPI>
__global__ __launch_bounds__(256) void gemm_bt(
    const u16* __restrict__ A,   // [M,K] bf16
    const u16* __restrict__ W,   // [N,K] bf16
    u16* __restrict__ outB,
    float* __restrict__ outF,
    const float* __restrict__ bias,
    int M, int N, int K)
{
    __shared__ u16 As[BM * LDST];
    __shared__ u16 Bs[BN * LDST];
    const int t    = threadIdx.x;
    const int wid  = t >> 6;
    const int lane = t & 63;
    const int lo   = lane & 15, hi = lane >> 4;
    const int bm   = blockIdx.x * BM;
    const int bn   = blockIdx.y * BN;
    const int wr   = wid >> 1, wc = wid & 1;

    f32x4 acc[4][4];
#pragma unroll
    for (int m = 0; m < 4; m++)
#pragma unroll
        for (int n = 0; n < 4; n++) acc[m][n] = (f32x4){0.f, 0.f, 0.f, 0.f};

    for (int k0 = 0; k0 < K; k0 += BK) {
        __syncthreads();
#pragma unroll
        for (int i = 0; i < 4; i++) {
            int a   = t + 256 * i;
            int row = a >> 3, ch = (a & 7) * 8;
            uint4 va = *reinterpret_cast<const uint4*>(A + (size_t)(bm + row) * K + k0 + ch);
            *reinterpret_cast<uint4*>(As + row * LDST + ch) = va;
            uint4 vb = *reinterpret_cast<const uint4*>(W + (size_t)(bn + row) * K + k0 + ch);
            *reinterpret_cast<uint4*>(Bs + row * LDST + ch) = vb;
        }
        __syncthreads();
#pragma unroll
        for (int h = 0; h < 2; h++) {
            bf16x8 af[4], bfr[4];
#pragma unroll
            for (int m = 0; m < 4; m++)
                af[m] = *reinterpret_cast<const bf16x8*>(As + (wr * 64 + m * 16 + lo) * LDST + h * 32 + hi * 8);
#pragma unroll
            for (int n = 0; n < 4; n++)
                bfr[n] = *reinterpret_cast<const bf16x8*>(Bs + (wc * 64 + n * 16 + lo) * LDST + h * 32 + hi * 8);
#pragma unroll
            for (int m = 0; m < 4; m++)
#pragma unroll
                for (int n = 0; n < 4; n++)
                    acc[m][n] = __builtin_amdgcn_mfma_f32_16x16x32_bf16(af[m], bfr[n], acc[m][n], 0, 0, 0);
        }
    }

#pragma unroll
    for (int m = 0; m < 4; m++) {
#pragma unroll
        for (int n = 0; n < 4; n++) {
#pragma unroll
            for (int r = 0; r < 4; r++) {
                int row = bm + wr * 64 + m * 16 + hi * 4 + r;
                int col = bn + wc * 64 + n * 16 + lo;
                float v = acc[m][n][r];
                if (EPI == 0) {
                    int b = row >> 11, np = row & 2047;
                    int hh = col >> 6, dd = col & 63;
                    outB[(((size_t)(b * NUM_HEADS + hh) * SEQ + np) << 6) + dd] = f2bf(v);
                } else {
                    outF[(size_t)row * N + col] = v + bias[col];
                }
            }
        }
    }
}

// ---------------- flash attention v3 -------------------------------------
// swapped QK^T (S^T in-register), swapped PV (O^T: cols=q -> lane-local
// rescale), gload_lds double-buffered prefetch with counted vmcnt + raw
// barriers, defer-max, setprio, LDS-transposed coalesced epilogue.
// grid: x = N/128 (reversed), y = B*H. 4 waves, 32 q rows/wave.

static __device__ __forceinline__ u32x2 tr16(unsigned int addr) {
    u32x2 r;
    asm volatile("ds_read_b64_tr_b16 %0, %1" : "=v"(r) : "v"(addr));
    return r;
}

__global__ __launch_bounds__(256, 4) void attn(
    const u16* __restrict__ Q,   // [B*H][N][64]
    const u16* __restrict__ Kg,
    const u16* __restrict__ Vg,
    u16* __restrict__ O)         // [B][N][H][64]
{
    // LDS map (u16 elems): K buf0 @0, K buf1 @4096, V buf0 @8192, V buf1 @12288
    // epilogue reuses [0..8703] as O-tile [128][68]
    __shared__ u16 lds[16384];
    const int t    = threadIdx.x;
    const int wid  = t >> 6, lane = t & 63;
    const int lo   = lane & 15, hi = lane >> 4;
    const int qt   = (int)gridDim.x - 1 - (int)blockIdx.x;   // longest blocks first
    const int bh   = blockIdx.y;
    const size_t base = (size_t)bh * SEQ * 64;
    const int qbase = qt * 128 + wid * 32;
    const unsigned ldsb = (unsigned)(uintptr_t)lds;

    // staging geometry: per-lane global source offsets for linear LDS dests.
    // K stored XOR-swizzled: LDS slot o holds K[o>>6][ (((o&63)*2)^(((o>>6)&7)<<4))>>1 ]
    // V stored subtiled:    slot o holds V[(o>>9>>2)*32+((o>>4)&31)][((o>>9)&3)*16+(o&15)]
    int srcK[2], srcV[2];
    unsigned dstK[2], dstV[2];
#pragma unroll
    for (int ti = 0; ti < 2; ti++) {
        int o   = t * 8 + ti * 2048;
        int row = o >> 6;
        int colb = ((o & 63) * 2) ^ ((row & 7) << 4);
        srcK[ti] = row * 64 + (colb >> 1);
        dstK[ti] = ldsb + o * 2;
        int st = o >> 9;
        int kv = (st >> 2) * 32 + ((o >> 4) & 31);
        int d  = (st & 3) * 16 + (o & 15);
        srcV[ti] = kv * 64 + d;
        dstV[ti] = ldsb + 16384 + o * 2;
    }

    // Q fragments (B-operand): lane holds Q[qbase+m*16+lo][h*32+hi*8+..]
    bf16x8 qf[2][2];
#pragma unroll
    for (int m = 0; m < 2; m++)
#pragma unroll
        for (int h = 0; h < 2; h++)
            qf[m][h] = *reinterpret_cast<const bf16x8*>(Q + base + (size_t)(qbase + m * 16 + lo) * 64 + h * 32 + hi * 8);
    // pin qf now so the compiler's vmcnt for these loads lands here, not in-loop
    asm volatile("" : "+v"(qf[0][0]), "+v"(qf[0][1]), "+v"(qf[1][0]), "+v"(qf[1][1]));

    float m_run[2], l_part[2];
    f32x4 acc[2][4];
#pragma unroll
    for (int m = 0; m < 2; m++) {
        m_run[m] = -3.0e38f; l_part[m] = 0.f;
#pragma unroll
        for (int dt = 0; dt < 4; dt++) acc[m][dt] = (f32x4){0.f, 0.f, 0.f, 0.f};
    }

    const int jmax_blk = 2 * qt + 1;
    const int jmax_wav = (qbase + 31) >> 6;
    const float C = 0.125f * 1.44269504f;   // scale * log2(e)

    // prologue: stage tile 0 -> buf 0
    {
        const u16* Kt = Kg + base;
        const u16* Vt = Vg + base;
#pragma unroll
        for (int ti = 0; ti < 2; ti++) {
            gload16(Kt + srcK[ti], dstK[ti]);
            gload16(Vt + srcV[ti], dstV[ti]);
        }
    }

    for (int j = 0; j <= jmax_blk; j++) {
        const int cur = j & 1;
        if (j < jmax_blk) {
            const u16* Kt = Kg + base + (size_t)(j + 1) * 4096;
            const u16* Vt = Vg + base + (size_t)(j + 1) * 4096;
            const unsigned bs = (unsigned)(((j + 1) & 1) * 8192);
#pragma unroll
            for (int ti = 0; ti < 2; ti++) {
                gload16(Kt + srcK[ti], dstK[ti] + bs);
                gload16(Vt + srcV[ti], dstV[ti] + bs);
            }
            asm volatile("s_waitcnt vmcnt(4)" ::: "memory");   // tile j landed; j+1 in flight
        } else {
            asm volatile("s_waitcnt vmcnt(0)" ::: "memory");
        }
        __builtin_amdgcn_s_barrier();
        __builtin_amdgcn_sched_barrier(0);

        if (j <= jmax_wav) {
            const char* Kcur = (const char*)lds + cur * 8192;
            // K fragments (A-operand) from swizzled LDS
            bf16x8 kf[4][2];
#pragma unroll
            for (int kt = 0; kt < 4; kt++)
#pragma unroll
                for (int h = 0; h < 2; h++)
                    kf[kt][h] = *reinterpret_cast<const bf16x8*>(
                        Kcur + (kt * 16 + lo) * 128 + ((h * 64 + hi * 16) ^ ((lo & 7) << 4)));

            bf16x8 pa[2][2];
#pragma unroll
            for (int m = 0; m < 2; m++) {
                // S^T = K Q^T: lane holds S[q=qbase+m*16+lo][kv=j*64+kt*16+hi*4+r]
                f32x4 s[4];
                __builtin_amdgcn_s_setprio(1);
#pragma unroll
                for (int kt = 0; kt < 4; kt++) {
                    f32x4 a = (f32x4){0.f, 0.f, 0.f, 0.f};
#pragma unroll
                    for (int h = 0; h < 2; h++)
                        a = __builtin_amdgcn_mfma_f32_16x16x32_bf16(kf[kt][h], qf[m][h], a, 0, 0, 0);
                    s[kt] = a * C;
                }
                __builtin_amdgcn_s_setprio(0);
                const int qfb = qbase + m * 16;
                if (j * 64 + 63 > qfb) {    // diagonal: causal mask
                    const int q = qfb + lo;
#pragma unroll
                    for (int kt = 0; kt < 4; kt++)
#pragma unroll
                        for (int r = 0; r < 4; r++)
                            if (j * 64 + kt * 16 + hi * 4 + r > q) s[kt][r] = -1.0e30f;
                }
                // online softmax, defer-max (THR=8 in log2 domain)
                float vm = s[0][0];
#pragma unroll
                for (int kt = 0; kt < 4; kt++)
#pragma unroll
                    for (int r = 0; r < 4; r++) vm = fmaxf(vm, s[kt][r]);
                vm = fmaxf(vm, __shfl_xor(vm, 16));
                vm = fmaxf(vm, __shfl_xor(vm, 32));
                if (!__all(vm <= m_run[m] + 8.0f)) {
                    float nm = fmaxf(m_run[m], vm);
                    float sc = exp2f(m_run[m] - nm);
                    m_run[m] = nm;
                    l_part[m] *= sc;
#pragma unroll
                    for (int dt = 0; dt < 4; dt++)
#pragma unroll
                        for (int r = 0; r < 4; r++) acc[m][dt][r] *= sc;   // cols=q=lo: lane-local!
                }
                float ps = 0.f;
#pragma unroll
                for (int kt = 0; kt < 4; kt++)
#pragma unroll
                    for (int r = 0; r < 4; r++) {
                        float p = exp2f(s[kt][r] - m_run[m]);
                        s[kt][r] = p;
                        ps += p;
                    }
                l_part[m] += ps;   // in-lane partial; cross-lane sum deferred to epilogue
                // pack P into PV fragments (kappa: e<4 -> kv=4hi+e; e>=4 -> 16+4hi+(e-4))
                union { u16 u[8]; bf16x8 v; } pk0, pk1;
#pragma unroll
                for (int e = 0; e < 4; e++) {
                    pk0.u[e]     = f2bf(s[0][e]);
                    pk0.u[4 + e] = f2bf(s[1][e]);
                    pk1.u[e]     = f2bf(s[2][e]);
                    pk1.u[4 + e] = f2bf(s[3][e]);
                }
                pa[m][0] = pk0.v;
                pa[m][1] = pk1.v;
            }

            // PV with SWAPPED operands: acc = mfma(A=V^T frag, B=P frag)
            // -> C[row=d][col=q=lo]: rescale/div are lane-local.
            const unsigned vtb = ldsb + 16384u + (unsigned)(cur * 8192) + (unsigned)((hi * 64 + lo * 4) * 2);
#pragma unroll
            for (int pr = 0; pr < 2; pr++) {       // dt pairs: keeps tv live-set at 16 VGPR
                u32x2 tv[2][2][2];
#pragma unroll
                for (int d2 = 0; d2 < 2; d2++)
#pragma unroll
                    for (int h = 0; h < 2; h++)
#pragma unroll
                        for (int sel = 0; sel < 2; sel++)
                            tv[d2][h][sel] = tr16(vtb + (unsigned)(((h * 4 + pr * 2 + d2) * 512 + sel * 256) * 2));
                asm volatile("s_waitcnt lgkmcnt(0)" ::: "memory");
                __builtin_amdgcn_sched_barrier(0);
                __builtin_amdgcn_s_setprio(1);
#pragma unroll
                for (int d2 = 0; d2 < 2; d2++) {
#pragma unroll
                    for (int h = 0; h < 2; h++) {
                        union { unsigned int w[4]; bf16x8 v; } bv;
                        bv.w[0] = tv[d2][h][0][0];
                        bv.w[1] = tv[d2][h][0][1];
                        bv.w[2] = tv[d2][h][1][0];
                        bv.w[3] = tv[d2][h][1][1];
#pragma unroll
                        for (int m = 0; m < 2; m++)
                            acc[m][pr * 2 + d2] = __builtin_amdgcn_mfma_f32_16x16x32_bf16(bv.v, pa[m][h], acc[m][pr * 2 + d2], 0, 0, 0);
                    }
                }
                __builtin_amdgcn_s_setprio(0);
            }
        }
        __builtin_amdgcn_s_barrier();
    }

    // epilogue: finish l across lane groups, normalize, transpose via LDS, store
    float inv[2];
#pragma unroll
    for (int m = 0; m < 2; m++) {
        float l = l_part[m];
        l += __shfl_xor(l, 16);
        l += __shfl_xor(l, 32);
        inv[m] = 1.0f / l;
    }
    // acc[m][dt][r]: q = qbase+m*16+lo, d = dt*16+hi*4+r -> LDS O-tile [128][68]
#pragma unroll
    for (int m = 0; m < 2; m++)
#pragma unroll
        for (int dt = 0; dt < 4; dt++) {
            union { u16 u[4]; uint2 d2; } pk;
#pragma unroll
            for (int r = 0; r < 4; r++) pk.u[r] = f2bf(acc[m][dt][r] * inv[m]);
            *reinterpret_cast<uint2*>(lds + (wid * 32 + m * 16 + lo) * 68 + dt * 16 + hi * 4) = pk.d2;
        }
    __syncthreads();
    const int b = bh >> 4, hh = bh & 15;
#pragma unroll
    for (int i = 0; i < 4; i++) {
        int c = t + 256 * i;
        int row = c >> 3, d0 = (c & 7) * 8;
        uint2 a0 = *reinterpret_cast<const uint2*>(lds + row * 68 + d0);
        uint2 a1 = *reinterpret_cast<const uint2*>(lds + row * 68 + d0 + 4);
        uint4 o4 = make_uint4(a0.x, a0.y, a1.x, a1.y);
        *reinterpret_cast<uint4*>(O + ((size_t)(b * SEQ + qt * 128 + row)) * 1024 + hh * 64 + d0) = o4;
    }
}

extern "C" void kernel_launch(void* const* d_in, const int* in_sizes, int n_in,
                              void* d_out, int out_size, void* d_ws, size_t ws_size,
                              hipStream_t stream) {
    const float* x  = (const float*)d_in[0];
    const float* Wq = (const float*)d_in[1];
    const float* Wk = (const float*)d_in[2];
    const float* Wv = (const float*)d_in[3];
    const float* Wo = (const float*)d_in[4];
    const float* bo = (const float*)d_in[5];
    float* out = (float*)d_out;

    char* ws = (char*)d_ws;
    u16* xb  = (u16*)ws;                              // 16 MiB
    u16* wqb = (u16*)(ws + 16777216);
    u16* wkb = wqb + 1048576;
    u16* wvb = wkb + 1048576;
    u16* wob = wvb + 1048576;
    u16* q   = (u16*)(ws + 16777216 + 8388608);       // [B][H][N][D] bf16
    u16* k   = q + 8388608;
    u16* v   = k + 8388608;
    u16* ao  = v + 8388608;                           // [B][N][H*D] bf16

    castk<<<2048, 256, 0, stream>>>(x,  xb,  ROWS * MODEL_DIM);
    castk<<<1024, 256, 0, stream>>>(Wq, wqb, MODEL_DIM * MODEL_DIM);
    castk<<<1024, 256, 0, stream>>>(Wk, wkb, MODEL_DIM * MODEL_DIM);
    castk<<<1024, 256, 0, stream>>>(Wv, wvb, MODEL_DIM * MODEL_DIM);
    castk<<<1024, 256, 0, stream>>>(Wo, wob, MODEL_DIM * MODEL_DIM);

    dim3 ggrid(ROWS / BM, MODEL_DIM / BN);
    gemm_bt<0><<<ggrid, 256, 0, stream>>>(xb, wqb, q, nullptr, nullptr, ROWS, MODEL_DIM, MODEL_DIM);
    gemm_bt<0><<<ggrid, 256, 0, stream>>>(xb, wkb, k, nullptr, nullptr, ROWS, MODEL_DIM, MODEL_DIM);
    gemm_bt<0><<<ggrid, 256, 0, stream>>>(xb, wvb, v, nullptr, nullptr, ROWS, MODEL_DIM, MODEL_DIM);

    attn<<<dim3(SEQ / 128, BATCH * NUM_HEADS), 256, 0, stream>>>(q, k, v, ao);

    gemm_bt<1><<<ggrid, 256, 0, stream>>>(ao, wob, nullptr, out, bo, ROWS, MODEL_DIM, MODEL_DIM);
}

// Round 4
// 219.914 us; speedup vs baseline: 2.0110x; 1.2807x over previous
//
#include <hip/hip_runtime.h>
#include <hip/hip_bf16.h>

typedef unsigned short u16;
typedef __attribute__((ext_vector_type(8))) __bf16 bf16x8;
typedef __attribute__((ext_vector_type(4))) float f32x4;
typedef __attribute__((ext_vector_type(2))) unsigned int u32x2;

#define MODEL_DIM 1024
#define NUM_HEADS 16
#define HEAD_DIM  64
#define BATCH     4
#define SEQ       2048
#define ROWS      (BATCH*SEQ)     // 8192

static __device__ __forceinline__ u16 f2bf(float f) {
    union { __hip_bfloat16 h; u16 u; } cv;
    cv.h = __float2bfloat16(f);
    return cv.u;
}

static __device__ __forceinline__ void gload16(const u16* g, unsigned lds_byte) {
    __builtin_amdgcn_global_load_lds(
        (const __attribute__((address_space(1))) unsigned int*)g,
        (__attribute__((address_space(3))) unsigned int*)(uintptr_t)lds_byte,
        16, 0, 0);
}

// ---------------- fused cast f32 -> bf16 (x + 4 weights, contiguous out) ----
__global__ void castk_all(const float* __restrict__ x,
                          const float* __restrict__ w0, const float* __restrict__ w1,
                          const float* __restrict__ w2, const float* __restrict__ w3,
                          u16* __restrict__ out) {
    const int total = ROWS * MODEL_DIM + 4 * MODEL_DIM * MODEL_DIM;  // 12.58M
    int i = (blockIdx.x * blockDim.x + threadIdx.x) * 4;
    int stride = gridDim.x * blockDim.x * 4;
    for (; i < total; i += stride) {
        const float* src;
        int off;
        if (i < ROWS * MODEL_DIM) { src = x; off = i; }
        else {
            int j = i - ROWS * MODEL_DIM;
            int w = j >> 20;
            off = j & 1048575;
            src = (w == 0) ? w0 : (w == 1) ? w1 : (w == 2) ? w2 : w3;
        }
        float4 v = *reinterpret_cast<const float4*>(src + off);
        ushort4 o;
        o.x = f2bf(v.x); o.y = f2bf(v.y); o.z = f2bf(v.z); o.w = f2bf(v.w);
        *reinterpret_cast<ushort4*>(out + i) = o;
    }
}

// ---------------- NT GEMM core macros ----------------
#define BM 128
#define BN 128
#define BK 64
#define LDST 72

// fused QKV projection: grid (M/128, 24); blockIdx.y selects matrix + col block
__global__ __launch_bounds__(256) void gemm_qkv(
    const u16* __restrict__ A,
    const u16* __restrict__ Wq, const u16* __restrict__ Wk, const u16* __restrict__ Wv,
    u16* __restrict__ qO, u16* __restrict__ kO, u16* __restrict__ vO)
{
    __shared__ u16 As[BM * LDST];
    __shared__ u16 Bs[BN * LDST];
    const int t    = threadIdx.x;
    const int wid  = t >> 6;
    const int lane = t & 63;
    const int lo   = lane & 15, hi = lane >> 4;
    const int bm   = blockIdx.x * BM;
    const int mat  = blockIdx.y >> 3;
    const int bn   = (blockIdx.y & 7) * BN;
    const u16* W   = (mat == 0) ? Wq : (mat == 1) ? Wk : Wv;
    u16* outB      = (mat == 0) ? qO : (mat == 1) ? kO : vO;
    const int wr   = wid >> 1, wc = wid & 1;
    const int K = MODEL_DIM;

    f32x4 acc[4][4];
#pragma unroll
    for (int m = 0; m < 4; m++)
#pragma unroll
        for (int n = 0; n < 4; n++) acc[m][n] = (f32x4){0.f, 0.f, 0.f, 0.f};

    for (int k0 = 0; k0 < K; k0 += BK) {
        __syncthreads();
#pragma unroll
        for (int i = 0; i < 4; i++) {
            int a   = t + 256 * i;
            int row = a >> 3, ch = (a & 7) * 8;
            uint4 va = *reinterpret_cast<const uint4*>(A + (size_t)(bm + row) * K + k0 + ch);
            *reinterpret_cast<uint4*>(As + row * LDST + ch) = va;
            uint4 vb = *reinterpret_cast<const uint4*>(W + (size_t)(bn + row) * K + k0 + ch);
            *reinterpret_cast<uint4*>(Bs + row * LDST + ch) = vb;
        }
        __syncthreads();
#pragma unroll
        for (int h = 0; h < 2; h++) {
            bf16x8 af[4], bfr[4];
#pragma unroll
            for (int m = 0; m < 4; m++)
                af[m] = *reinterpret_cast<const bf16x8*>(As + (wr * 64 + m * 16 + lo) * LDST + h * 32 + hi * 8);
#pragma unroll
            for (int n = 0; n < 4; n++)
                bfr[n] = *reinterpret_cast<const bf16x8*>(Bs + (wc * 64 + n * 16 + lo) * LDST + h * 32 + hi * 8);
#pragma unroll
            for (int m = 0; m < 4; m++)
#pragma unroll
                for (int n = 0; n < 4; n++)
                    acc[m][n] = __builtin_amdgcn_mfma_f32_16x16x32_bf16(af[m], bfr[n], acc[m][n], 0, 0, 0);
        }
    }

#pragma unroll
    for (int m = 0; m < 4; m++)
#pragma unroll
        for (int n = 0; n < 4; n++)
#pragma unroll
            for (int r = 0; r < 4; r++) {
                int row = bm + wr * 64 + m * 16 + hi * 4 + r;
                int col = bn + wc * 64 + n * 16 + lo;
                int b = row >> 11, np = row & 2047;
                int hh = col >> 6, dd = col & 63;
                outB[(((size_t)(b * NUM_HEADS + hh) * SEQ + np) << 6) + dd] = f2bf(acc[m][n][r]);
            }
}

// out-projection: C = A * Wo^T + bias, f32 out
__global__ __launch_bounds__(256) void gemm_out(
    const u16* __restrict__ A,
    const u16* __restrict__ W,
    float* __restrict__ outF,
    const float* __restrict__ bias)
{
    __shared__ u16 As[BM * LDST];
    __shared__ u16 Bs[BN * LDST];
    const int t    = threadIdx.x;
    const int wid  = t >> 6;
    const int lane = t & 63;
    const int lo   = lane & 15, hi = lane >> 4;
    const int bm   = blockIdx.x * BM;
    const int bn   = blockIdx.y * BN;
    const int wr   = wid >> 1, wc = wid & 1;
    const int K = MODEL_DIM, N = MODEL_DIM;

    f32x4 acc[4][4];
#pragma unroll
    for (int m = 0; m < 4; m++)
#pragma unroll
        for (int n = 0; n < 4; n++) acc[m][n] = (f32x4){0.f, 0.f, 0.f, 0.f};

    for (int k0 = 0; k0 < K; k0 += BK) {
        __syncthreads();
#pragma unroll
        for (int i = 0; i < 4; i++) {
            int a   = t + 256 * i;
            int row = a >> 3, ch = (a & 7) * 8;
            uint4 va = *reinterpret_cast<const uint4*>(A + (size_t)(bm + row) * K + k0 + ch);
            *reinterpret_cast<uint4*>(As + row * LDST + ch) = va;
            uint4 vb = *reinterpret_cast<const uint4*>(W + (size_t)(bn + row) * K + k0 + ch);
            *reinterpret_cast<uint4*>(Bs + row * LDST + ch) = vb;
        }
        __syncthreads();
#pragma unroll
        for (int h = 0; h < 2; h++) {
            bf16x8 af[4], bfr[4];
#pragma unroll
            for (int m = 0; m < 4; m++)
                af[m] = *reinterpret_cast<const bf16x8*>(As + (wr * 64 + m * 16 + lo) * LDST + h * 32 + hi * 8);
#pragma unroll
            for (int n = 0; n < 4; n++)
                bfr[n] = *reinterpret_cast<const bf16x8*>(Bs + (wc * 64 + n * 16 + lo) * LDST + h * 32 + hi * 8);
#pragma unroll
            for (int m = 0; m < 4; m++)
#pragma unroll
                for (int n = 0; n < 4; n++)
                    acc[m][n] = __builtin_amdgcn_mfma_f32_16x16x32_bf16(af[m], bfr[n], acc[m][n], 0, 0, 0);
        }
    }

#pragma unroll
    for (int m = 0; m < 4; m++)
#pragma unroll
        for (int n = 0; n < 4; n++)
#pragma unroll
            for (int r = 0; r < 4; r++) {
                int row = bm + wr * 64 + m * 16 + hi * 4 + r;
                int col = bn + wc * 64 + n * 16 + lo;
                outF[(size_t)row * N + col] = acc[m][n][r] + bias[col];
            }
}

// ---------------- flash attention v4 -------------------------------------
// v3 core (swapped QK^T/PV, gload_lds dbuf, counted vmcnt, defer-max,
// setprio, LDS-transposed epilogue) + per-CU work-balance XOR swizzle:
// CU's 4 step-256 blocks get qt = {b, 15-b, b^5, 15-(b^5)} -> 68 iters/CU exact.

static __device__ __forceinline__ u32x2 tr16(unsigned int addr) {
    u32x2 r;
    asm volatile("ds_read_b64_tr_b16 %0, %1" : "=v"(r) : "v"(addr));
    return r;
}

__global__ __launch_bounds__(256, 4) void attn(
    const u16* __restrict__ Q,   // [B*H][N][64]
    const u16* __restrict__ Kg,
    const u16* __restrict__ Vg,
    u16* __restrict__ O)         // [B][N][H][64]
{
    __shared__ u16 lds[16384];
    const int t    = threadIdx.x;
    const int wid  = t >> 6, lane = t & 63;
    const int lo   = lane & 15, hi = lane >> 4;
    const int y    = blockIdx.y;
    const int xt   = (0xA5F0 >> (((y >> 4) & 3) * 4)) & 15;   // {0,15,5,10}
    const int qt   = (((int)blockIdx.x + y) & 15) ^ xt;        // balanced bijection
    const int bh   = y;
    const size_t base = (size_t)bh * SEQ * 64;
    const int qbase = qt * 128 + wid * 32;
    const unsigned ldsb = (unsigned)(uintptr_t)lds;

    int srcK[2], srcV[2];
    unsigned dstK[2], dstV[2];
#pragma unroll
    for (int ti = 0; ti < 2; ti++) {
        int o   = t * 8 + ti * 2048;
        int row = o >> 6;
        int colb = ((o & 63) * 2) ^ ((row & 7) << 4);
        srcK[ti] = row * 64 + (colb >> 1);
        dstK[ti] = ldsb + o * 2;
        int st = o >> 9;
        int kv = (st >> 2) * 32 + ((o >> 4) & 31);
        int d  = (st & 3) * 16 + (o & 15);
        srcV[ti] = kv * 64 + d;
        dstV[ti] = ldsb + 16384 + o * 2;
    }

    bf16x8 qf[2][2];
#pragma unroll
    for (int m = 0; m < 2; m++)
#pragma unroll
        for (int h = 0; h < 2; h++)
            qf[m][h] = *reinterpret_cast<const bf16x8*>(Q + base + (size_t)(qbase + m * 16 + lo) * 64 + h * 32 + hi * 8);
    asm volatile("" : "+v"(qf[0][0]), "+v"(qf[0][1]), "+v"(qf[1][0]), "+v"(qf[1][1]));

    float m_run[2], l_part[2];
    f32x4 acc[2][4];
#pragma unroll
    for (int m = 0; m < 2; m++) {
        m_run[m] = -3.0e38f; l_part[m] = 0.f;
#pragma unroll
        for (int dt = 0; dt < 4; dt++) acc[m][dt] = (f32x4){0.f, 0.f, 0.f, 0.f};
    }

    const int jmax_blk = 2 * qt + 1;
    const int jmax_wav = (qbase + 31) >> 6;
    const float C = 0.125f * 1.44269504f;

    {
        const u16* Kt = Kg + base;
        const u16* Vt = Vg + base;
#pragma unroll
        for (int ti = 0; ti < 2; ti++) {
            gload16(Kt + srcK[ti], dstK[ti]);
            gload16(Vt + srcV[ti], dstV[ti]);
        }
    }

    for (int j = 0; j <= jmax_blk; j++) {
        const int cur = j & 1;
        if (j < jmax_blk) {
            const u16* Kt = Kg + base + (size_t)(j + 1) * 4096;
            const u16* Vt = Vg + base + (size_t)(j + 1) * 4096;
            const unsigned bs = (unsigned)(((j + 1) & 1) * 8192);
#pragma unroll
            for (int ti = 0; ti < 2; ti++) {
                gload16(Kt + srcK[ti], dstK[ti] + bs);
                gload16(Vt + srcV[ti], dstV[ti] + bs);
            }
            asm volatile("s_waitcnt vmcnt(4)" ::: "memory");
        } else {
            asm volatile("s_waitcnt vmcnt(0)" ::: "memory");
        }
        __builtin_amdgcn_s_barrier();
        __builtin_amdgcn_sched_barrier(0);

        if (j <= jmax_wav) {
            const char* Kcur = (const char*)lds + cur * 8192;
            bf16x8 kf[4][2];
#pragma unroll
            for (int kt = 0; kt < 4; kt++)
#pragma unroll
                for (int h = 0; h < 2; h++)
                    kf[kt][h] = *reinterpret_cast<const bf16x8*>(
                        Kcur + (kt * 16 + lo) * 128 + ((h * 64 + hi * 16) ^ ((lo & 7) << 4)));

            bf16x8 pa[2][2];
#pragma unroll
            for (int m = 0; m < 2; m++) {
                f32x4 s[4];
                __builtin_amdgcn_s_setprio(1);
#pragma unroll
                for (int kt = 0; kt < 4; kt++) {
                    f32x4 a = (f32x4){0.f, 0.f, 0.f, 0.f};
#pragma unroll
                    for (int h = 0; h < 2; h++)
                        a = __builtin_amdgcn_mfma_f32_16x16x32_bf16(kf[kt][h], qf[m][h], a, 0, 0, 0);
                    s[kt] = a * C;
                }
                __builtin_amdgcn_s_setprio(0);
                const int qfb = qbase + m * 16;
                if (j * 64 + 63 > qfb) {
                    const int q = qfb + lo;
#pragma unroll
                    for (int kt = 0; kt < 4; kt++)
#pragma unroll
                        for (int r = 0; r < 4; r++)
                            if (j * 64 + kt * 16 + hi * 4 + r > q) s[kt][r] = -1.0e30f;
                }
                float vm = s[0][0];
#pragma unroll
                for (int kt = 0; kt < 4; kt++)
#pragma unroll
                    for (int r = 0; r < 4; r++) vm = fmaxf(vm, s[kt][r]);
                vm = fmaxf(vm, __shfl_xor(vm, 16));
                vm = fmaxf(vm, __shfl_xor(vm, 32));
                if (!__all(vm <= m_run[m] + 8.0f)) {
                    float nm = fmaxf(m_run[m], vm);
                    float sc = exp2f(m_run[m] - nm);
                    m_run[m] = nm;
                    l_part[m] *= sc;
#pragma unroll
                    for (int dt = 0; dt < 4; dt++)
#pragma unroll
                        for (int r = 0; r < 4; r++) acc[m][dt][r] *= sc;
                }
                float ps = 0.f;
#pragma unroll
                for (int kt = 0; kt < 4; kt++)
#pragma unroll
                    for (int r = 0; r < 4; r++) {
                        float p = exp2f(s[kt][r] - m_run[m]);
                        s[kt][r] = p;
                        ps += p;
                    }
                l_part[m] += ps;
                union { u16 u[8]; bf16x8 v; } pk0, pk1;
#pragma unroll
                for (int e = 0; e < 4; e++) {
                    pk0.u[e]     = f2bf(s[0][e]);
                    pk0.u[4 + e] = f2bf(s[1][e]);
                    pk1.u[e]     = f2bf(s[2][e]);
                    pk1.u[4 + e] = f2bf(s[3][e]);
                }
                pa[m][0] = pk0.v;
                pa[m][1] = pk1.v;
            }

            const unsigned vtb = ldsb + 16384u + (unsigned)(cur * 8192) + (unsigned)((hi * 64 + lo * 4) * 2);
#pragma unroll
            for (int pr = 0; pr < 2; pr++) {
                u32x2 tv[2][2][2];
#pragma unroll
                for (int d2 = 0; d2 < 2; d2++)
#pragma unroll
                    for (int h = 0; h < 2; h++)
#pragma unroll
                        for (int sel = 0; sel < 2; sel++)
                            tv[d2][h][sel] = tr16(vtb + (unsigned)(((h * 4 + pr * 2 + d2) * 512 + sel * 256) * 2));
                asm volatile("s_waitcnt lgkmcnt(0)" ::: "memory");
                __builtin_amdgcn_sched_barrier(0);
                __builtin_amdgcn_s_setprio(1);
#pragma unroll
                for (int d2 = 0; d2 < 2; d2++) {
#pragma unroll
                    for (int h = 0; h < 2; h++) {
                        union { unsigned int w[4]; bf16x8 v; } bv;
                        bv.w[0] = tv[d2][h][0][0];
                        bv.w[1] = tv[d2][h][0][1];
                        bv.w[2] = tv[d2][h][1][0];
                        bv.w[3] = tv[d2][h][1][1];
#pragma unroll
                        for (int m = 0; m < 2; m++)
                            acc[m][pr * 2 + d2] = __builtin_amdgcn_mfma_f32_16x16x32_bf16(bv.v, pa[m][h], acc[m][pr * 2 + d2], 0, 0, 0);
                    }
                }
                __builtin_amdgcn_s_setprio(0);
            }
        }
        __builtin_amdgcn_s_barrier();
    }

    float inv[2];
#pragma unroll
    for (int m = 0; m < 2; m++) {
        float l = l_part[m];
        l += __shfl_xor(l, 16);
        l += __shfl_xor(l, 32);
        inv[m] = 1.0f / l;
    }
#pragma unroll
    for (int m = 0; m < 2; m++)
#pragma unroll
        for (int dt = 0; dt < 4; dt++) {
            union { u16 u[4]; uint2 d2; } pk;
#pragma unroll
            for (int r = 0; r < 4; r++) pk.u[r] = f2bf(acc[m][dt][r] * inv[m]);
            *reinterpret_cast<uint2*>(lds + (wid * 32 + m * 16 + lo) * 68 + dt * 16 + hi * 4) = pk.d2;
        }
    __syncthreads();
    const int b = bh >> 4, hh = bh & 15;
#pragma unroll
    for (int i = 0; i < 4; i++) {
        int c = t + 256 * i;
        int row = c >> 3, d0 = (c & 7) * 8;
        uint2 a0 = *reinterpret_cast<const uint2*>(lds + row * 68 + d0);
        uint2 a1 = *reinterpret_cast<const uint2*>(lds + row * 68 + d0 + 4);
        uint4 o4 = make_uint4(a0.x, a0.y, a1.x, a1.y);
        *reinterpret_cast<uint4*>(O + ((size_t)(b * SEQ + qt * 128 + row)) * 1024 + hh * 64 + d0) = o4;
    }
}

extern "C" void kernel_launch(void* const* d_in, const int* in_sizes, int n_in,
                              void* d_out, int out_size, void* d_ws, size_t ws_size,
                              hipStream_t stream) {
    const float* x  = (const float*)d_in[0];
    const float* Wq = (const float*)d_in[1];
    const float* Wk = (const float*)d_in[2];
    const float* Wv = (const float*)d_in[3];
    const float* Wo = (const float*)d_in[4];
    const float* bo = (const float*)d_in[5];
    float* out = (float*)d_out;

    char* ws = (char*)d_ws;
    u16* xb  = (u16*)ws;                              // 16 MiB, then weights contiguous
    u16* wqb = (u16*)(ws + 16777216);
    u16* wkb = wqb + 1048576;
    u16* wvb = wkb + 1048576;
    u16* wob = wvb + 1048576;
    u16* q   = (u16*)(ws + 16777216 + 8388608);       // [B][H][N][D] bf16
    u16* k   = q + 8388608;
    u16* v   = k + 8388608;
    u16* ao  = v + 8388608;                           // [B][N][H*D] bf16

    castk_all<<<3072, 256, 0, stream>>>(x, Wq, Wk, Wv, Wo, xb);

    gemm_qkv<<<dim3(ROWS / BM, 24), 256, 0, stream>>>(xb, wqb, wkb, wvb, q, k, v);

    attn<<<dim3(SEQ / 128, BATCH * NUM_HEADS), 256, 0, stream>>>(q, k, v, ao);

    gemm_out<<<dim3(ROWS / BM, MODEL_DIM / BN), 256, 0, stream>>>(ao, wob, out, bo);
}